// Round 13
// baseline (336.530 us; speedup 1.0000x reference)
//
#include <hip/hip_runtime.h>
#include <hip/hip_bf16.h>

#define N_NODES 50000
#define N_EDGES 800000
#define N_GRAPHS 64
#define CAP 64  // bucket capacity; deg ~ Binom(800k,1/50k), P(deg>64) ~ 1e-19

typedef __attribute__((ext_vector_type(8))) short bf16x8;
typedef __attribute__((ext_vector_type(4))) float f32x4;

#define AS1 __attribute__((address_space(1)))
#define AS3 __attribute__((address_space(3)))

__device__ __forceinline__ float bf2f(ushort u) { return __uint_as_float(((unsigned)u) << 16); }
__device__ __forceinline__ ushort f2bf(float f) {  // RNE
    unsigned b = __float_as_uint(f);
    b += 0x7fffu + ((b >> 16) & 1u);
    return (ushort)(b >> 16);
}

// async global->LDS, 16B per lane; LDS dest = wave-uniform base + lane*16 (linear)
__device__ __forceinline__ void gl_lds16(const ushort* g, ushort* l) {
    __builtin_amdgcn_global_load_lds((const AS1 void*)g, (AS3 void*)l, 16, 0, 0);
}

// ---------------------------------------------------------------- h0 = concat(x, pos) -> bf16
__global__ void build_h0(const float* __restrict__ x, const float* __restrict__ pos,
                         ushort* __restrict__ h0, int n) {
    const size_t total = (size_t)n * 128;
    for (size_t idx = (size_t)blockIdx.x * blockDim.x + threadIdx.x; idx < total;
         idx += (size_t)gridDim.x * blockDim.x) {
        int i = (int)(idx >> 7);
        int j = (int)(idx & 127);
        float v = (j < 125) ? x[(size_t)i * 125 + j] : pos[(size_t)i * 3 + (j - 125)];
        h0[idx] = f2bf(v);
    }
}

// ---------------------------------------------------------------- weights fp32 -> bf16
__global__ void convert_weights(const float* __restrict__ w0, const float* __restrict__ w1,
                                const float* __restrict__ w2, const float* __restrict__ w3,
                                const float* __restrict__ w4, const float* __restrict__ w5,
                                ushort* __restrict__ o) {
    const int total = 32768 * 2 + 65536 * 4;
    for (int i = blockIdx.x * blockDim.x + threadIdx.x; i < total; i += gridDim.x * blockDim.x) {
        float v;
        if (i < 32768) v = w0[i];
        else if (i < 65536) v = w1[i - 32768];
        else {
            int j = i - 65536;
            int m = j >> 16;
            int r = j & 65535;
            v = (m == 0) ? w2[r] : (m == 1) ? w3[r] : (m == 2) ? w4[r] : w5[r];
        }
        o[i] = f2bf(v);
    }
}

// ---------------------------------------------------------------- CSR build: single-pass buckets
// Fixed-capacity bucket per node (CAP=64); XCD-partitioned by dst range (blockIdx&7).
__global__ __launch_bounds__(256) void build_csr(const int* __restrict__ src,
                                                 const int* __restrict__ dst,
                                                 int* __restrict__ cnt,
                                                 ushort* __restrict__ csr, int e) {
    const int g = blockIdx.x & 7;
    const int bid = blockIdx.x >> 3;
    const int nb = gridDim.x >> 3;
    const int lo = g * (N_NODES / 8), hi = lo + (N_NODES / 8);
    for (int i = bid * blockDim.x + threadIdx.x; i < e; i += nb * blockDim.x) {
        const int d = dst[i];
        if (d >= lo && d < hi) {
            int pos = atomicAdd(&cnt[d], 1);
            if (pos < CAP) csr[(size_t)d * CAP + pos] = (ushort)src[i];
        }
    }
}

// ---------------------------------------------------------------- mean aggregation (gather, bf16)
// one wave per node; lane loads 16B (bf16x8). F=256: 2 edge-streams/wave; F=128: 4.
// Unroll x4 -> 8 (resp. 16) independent row loads in flight; singles tail.
// FETCH ~175MB is the structural floor (each XCD touches ~43k distinct rows).
template <int F>
__global__ __launch_bounds__(256) void csr_mean(const ushort* __restrict__ h,
                                                const int* __restrict__ cnt,
                                                const ushort* __restrict__ idx,
                                                ushort* __restrict__ s, int n) {
    const int node = blockIdx.x * 4 + (threadIdx.x >> 6);
    if (node >= n) return;
    const int lane = threadIdx.x & 63;
    constexpr int LPR = F / 8;        // lanes covering one row
    constexpr int EPW = 64 / LPR;     // edge streams per wave (2 or 4)
    const int sub = lane / LPR;       // edge-stream id
    const int l = lane % LPR;         // feature chunk (8 feats)
    const int b = node * CAP;
    const int c = min(cnt[node], CAP);

    float s0[8] = {}, s1[8] = {}, s2[8] = {}, s3[8] = {};
    const ushort* hl = h + (size_t)l * 8;
    int q = sub;
    for (; q + 3 * EPW < c; q += 4 * EPW) {
        int i0 = idx[b + q];
        int i1 = idx[b + q + EPW];
        int i2 = idx[b + q + 2 * EPW];
        int i3 = idx[b + q + 3 * EPW];
        bf16x8 v0 = *(const bf16x8*)(hl + (size_t)i0 * F);
        bf16x8 v1 = *(const bf16x8*)(hl + (size_t)i1 * F);
        bf16x8 v2 = *(const bf16x8*)(hl + (size_t)i2 * F);
        bf16x8 v3 = *(const bf16x8*)(hl + (size_t)i3 * F);
#pragma unroll
        for (int j = 0; j < 8; ++j) s0[j] += bf2f((ushort)v0[j]);
#pragma unroll
        for (int j = 0; j < 8; ++j) s1[j] += bf2f((ushort)v1[j]);
#pragma unroll
        for (int j = 0; j < 8; ++j) s2[j] += bf2f((ushort)v2[j]);
#pragma unroll
        for (int j = 0; j < 8; ++j) s3[j] += bf2f((ushort)v3[j]);
    }
    for (; q < c; q += EPW) {
        int i0 = idx[b + q];
        bf16x8 v0 = *(const bf16x8*)(hl + (size_t)i0 * F);
#pragma unroll
        for (int j = 0; j < 8; ++j) s0[j] += bf2f((ushort)v0[j]);
    }
    const float w = 1.0f / (float)max(c, 1);
    bf16x8 o;
#pragma unroll
    for (int j = 0; j < 8; ++j) {
        float a = (s0[j] + s1[j]) + (s2[j] + s3[j]);
        if constexpr (EPW == 4) a += __shfl_xor(a, 16);
        a += __shfl_xor(a, 32);
        o[j] = (short)f2bf(a * w);
    }
    if (sub == 0) *(bf16x8*)(s + (size_t)node * F + l * 8) = o;
}

// ---------------------------------------------------------------- fused SAGE GEMM (bf16 MFMA)
// BN=256 (full output width per block) -> A (S|H) is staged exactly ONCE (halves the
// dominant A-stream traffic vs grid.y=2). 4 waves, wave tile 64x128, acc f32x4[4][8].
// LDS: As 16KB + Bs 32KB = 48KB. Staging via global_load_lds w=16, XOR-swizzled source +
// swizzled ds_read (rule #21: linear dest, inverse-swz source, swz read).
__global__ __launch_bounds__(256, 2) void sage_gemm(
    const ushort* __restrict__ S, const ushort* __restrict__ H,
    const ushort* __restrict__ Wl, const ushort* __restrict__ Wr,
    const float* __restrict__ bias, ushort* __restrict__ O, int n, int F) {
    constexpr int BM = 128, BN = 256, BK = 64;
    __shared__ ushort As[BM * BK];
    __shared__ ushort Bs[BN * BK];
    const int row0 = blockIdx.x * BM;
    const int tid = threadIdx.x;
    const int wid = tid >> 6;
    const int wr = wid >> 1;     // 0..1 -> 64-row half
    const int wc = wid & 1;      // 0..1 -> 128-col half
    const int lane = tid & 63;
    const int lr = lane & 15;
    const int lk = lane >> 4;
    const int lrow = lane >> 3;  // staging: row within 8-row stripe
    const int lgg = lane & 7;    // staging: granule (16B) within row

    f32x4 acc[4][8] = {};

    const int Ktot = 2 * F;
    for (int kb = 0; kb < Ktot; kb += BK) {
        const bool left = (kb < F);
        const int kofs = left ? kb : kb - F;
        const ushort* __restrict__ Ab = left ? S : H;
        const ushort* __restrict__ Wb = left ? Wl : Wr;
        // ---- stage A (128 rows): 4 stripes/wave; B (256 rows): 8 stripes/wave ----
#pragma unroll
        for (int p = 0; p < 4; ++p) {
            const int rb = (p * 4 + wid) * 8;
            const int r = rb + lrow;
            const int sg = (lgg ^ (r & 7)) << 3;
            const int gr = min(row0 + r, n - 1);
            gl_lds16(Ab + (size_t)gr * F + kofs + sg, &As[rb * 64]);
        }
#pragma unroll
        for (int p = 0; p < 8; ++p) {
            const int rb = (p * 4 + wid) * 8;
            const int r = rb + lrow;
            const int sg = (lgg ^ (r & 7)) << 3;
            gl_lds16(Wb + (size_t)r * F + kofs + sg, &Bs[rb * 64]);
        }
        __syncthreads();
#pragma unroll
        for (int kh = 0; kh < 2; ++kh) {
            bf16x8 af[4], bg[8];
            const int g = kh * 4 + lk;  // source granule wanted
#pragma unroll
            for (int m = 0; m < 4; ++m) {
                const int ra = wr * 64 + m * 16 + lr;
                af[m] = *(const bf16x8*)&As[ra * 64 + ((g ^ (ra & 7)) << 3)];
            }
#pragma unroll
            for (int q = 0; q < 8; ++q) {
                const int rb2 = wc * 128 + q * 16 + lr;
                bg[q] = *(const bf16x8*)&Bs[rb2 * 64 + ((g ^ (rb2 & 7)) << 3)];
            }
#pragma unroll
            for (int m = 0; m < 4; ++m)
#pragma unroll
                for (int q = 0; q < 8; ++q)
                    acc[m][q] =
                        __builtin_amdgcn_mfma_f32_16x16x32_bf16(af[m], bg[q], acc[m][q], 0, 0, 0);
        }
        __syncthreads();
    }
    // epilogue: bias + relu -> bf16. C/D map: col = lane&15, row = (lane>>4)*4 + reg
#pragma unroll
    for (int q = 0; q < 8; ++q) {
        const int col = wc * 128 + q * 16 + lr;
        const float bv = bias[col];
#pragma unroll
        for (int m = 0; m < 4; ++m) {
            const int row = row0 + wr * 64 + m * 16 + lk * 4;
#pragma unroll
            for (int j = 0; j < 4; ++j) {
                if (row + j < n)
                    O[(size_t)(row + j) * 256 + col] = f2bf(fmaxf(acc[m][q][j] + bv, 0.f));
            }
        }
    }
}

// ---------------------------------------------------------------- global max pool (batch sorted)
__global__ __launch_bounds__(256) void pool_max(const ushort* __restrict__ h,
                                                const int* __restrict__ batch,
                                                int* __restrict__ gpool, int n) {
    const int CHUNK = 32;
    const int wave = threadIdx.x >> 6;
    const int lane = threadIdx.x & 63;
    const int c0 = (blockIdx.x * 4 + wave) * CHUNK;
    if (c0 >= n) return;
    const int c1 = min(c0 + CHUNK, n);
    const int fb = lane * 4;
    float m0 = 0.f, m1 = 0.f, m2 = 0.f, m3 = 0.f;
    int g = batch[c0];
    for (int i = c0; i < c1; ++i) {
        const int bg = batch[i];
        if (bg != g) {
            int* gp = &gpool[g * 256 + fb];
            atomicMax(gp + 0, __float_as_int(m0));
            atomicMax(gp + 1, __float_as_int(m1));
            atomicMax(gp + 2, __float_as_int(m2));
            atomicMax(gp + 3, __float_as_int(m3));
            m0 = m1 = m2 = m3 = 0.f;
            g = bg;
        }
        const ushort4 v = *(const ushort4*)(h + (size_t)i * 256 + fb);
        m0 = fmaxf(m0, bf2f(v.x));
        m1 = fmaxf(m1, bf2f(v.y));
        m2 = fmaxf(m2, bf2f(v.z));
        m3 = fmaxf(m3, bf2f(v.w));
    }
    int* gp = &gpool[g * 256 + fb];
    atomicMax(gp + 0, __float_as_int(m0));
    atomicMax(gp + 1, __float_as_int(m1));
    atomicMax(gp + 2, __float_as_int(m2));
    atomicMax(gp + 3, __float_as_int(m3));
}

// ---------------------------------------------------------------- head (fp32)
__global__ __launch_bounds__(256) void head_kernel(
    const float* __restrict__ gpool, const float* __restrict__ linW,
    const float* __restrict__ linb, const float* __restrict__ outW,
    const float* __restrict__ outb, float* __restrict__ out) {
    __shared__ float gin[256];
    __shared__ float gl[256];
    int g = blockIdx.x, t = threadIdx.x;
    gin[t] = gpool[g * 256 + t];
    __syncthreads();
    float acc = linb[t];
    const float* w = linW + (size_t)t * 256;
#pragma unroll 4
    for (int k = 0; k < 256; ++k) acc = fmaf(gin[k], w[k], acc);
    gl[t] = acc;
    __syncthreads();
    if (t < 160) {
        int o = t >> 4, s = t & 15;
        float p = 0.f;
        for (int k = s; k < 256; k += 16) p = fmaf(gl[k], outW[o * 256 + k], p);
        p += __shfl_down(p, 8, 16);
        p += __shfl_down(p, 4, 16);
        p += __shfl_down(p, 2, 16);
        p += __shfl_down(p, 1, 16);
        if (s == 0) out[g * 10 + o] = p + outb[o];
    }
}

// ---------------------------------------------------------------- launcher
extern "C" void kernel_launch(void* const* d_in, const int* in_sizes, int n_in,
                              void* d_out, int out_size, void* d_ws, size_t ws_size,
                              hipStream_t stream) {
    const float* x    = (const float*)d_in[0];
    const float* pos  = (const float*)d_in[1];
    const int* ei     = (const int*)d_in[2];
    const int* batch  = (const int*)d_in[3];
    const float* Wl0  = (const float*)d_in[4];
    const float* bl0  = (const float*)d_in[5];
    const float* Wr0  = (const float*)d_in[6];
    const float* Wl1  = (const float*)d_in[7];
    const float* bl1  = (const float*)d_in[8];
    const float* Wr1  = (const float*)d_in[9];
    const float* Wl2  = (const float*)d_in[10];
    const float* bl2  = (const float*)d_in[11];
    const float* Wr2  = (const float*)d_in[12];
    const float* linW = (const float*)d_in[13];
    const float* linb = (const float*)d_in[14];
    const float* outW = (const float*)d_in[15];
    const float* outb = (const float*)d_in[16];
    float* out = (float*)d_out;

    const int* src = ei;
    const int* dst = ei + N_EDGES;
    const int N = N_NODES, E = N_EDGES;

    // workspace layout
    ushort* hA   = (ushort*)d_ws;                // N*256 bf16
    ushort* hB   = hA + (size_t)N * 256;
    ushort* Sg   = hB + (size_t)N * 256;
    ushort* Wb   = Sg + (size_t)N * 256;         // 327680 shorts
    ushort* csr  = Wb + 327680;                  // N*CAP ushorts (6.4 MB)
    int* cnt     = (int*)(csr + (size_t)N * CAP);  // N
    int* gpool   = cnt + N;                      // 64*256

    ushort* Wl0b = Wb;
    ushort* Wr0b = Wb + 32768;
    ushort* Wl1b = Wb + 65536;
    ushort* Wr1b = Wb + 65536 + 65536;
    ushort* Wl2b = Wb + 65536 + 2 * 65536;
    ushort* Wr2b = Wb + 65536 + 3 * 65536;

    build_h0<<<dim3(1024), dim3(256), 0, stream>>>(x, pos, hA, N);
    convert_weights<<<dim3(640), dim3(256), 0, stream>>>(Wl0, Wr0, Wl1, Wr1, Wl2, Wr2, Wb);

    // CSR bucket build (dst-partitioned by XCD group), shared by all 3 layers
    hipMemsetAsync(cnt, 0, (size_t)N * sizeof(int), stream);
    build_csr<<<dim3(768), dim3(256), 0, stream>>>(src, dst, cnt, csr, E);

    const dim3 gemm_grid((N + 127) / 128, 1), blk(256);

    // layer 0: hA(128) -> hB(256)
    csr_mean<128><<<dim3((N + 3) / 4), blk, 0, stream>>>(hA, cnt, csr, Sg, N);
    sage_gemm<<<gemm_grid, blk, 0, stream>>>(Sg, hA, Wl0b, Wr0b, bl0, hB, N, 128);

    // layer 1: hB(256) -> hA(256)
    csr_mean<256><<<dim3((N + 3) / 4), blk, 0, stream>>>(hB, cnt, csr, Sg, N);
    sage_gemm<<<gemm_grid, blk, 0, stream>>>(Sg, hB, Wl1b, Wr1b, bl1, hA, N, 256);

    // layer 2: hA(256) -> hB(256)
    csr_mean<256><<<dim3((N + 3) / 4), blk, 0, stream>>>(hA, cnt, csr, Sg, N);
    sage_gemm<<<gemm_grid, blk, 0, stream>>>(Sg, hA, Wl2b, Wr2b, bl2, hB, N, 256);

    // pool + head
    hipMemsetAsync(gpool, 0, (size_t)N_GRAPHS * 256 * sizeof(int), stream);
    pool_max<<<dim3((N + 127) / 128), blk, 0, stream>>>(hB, batch, gpool, N);
    head_kernel<<<dim3(N_GRAPHS), blk, 0, stream>>>((const float*)gpool, linW, linb, outW, outb,
                                                    out);
}

// Round 14
// 310.368 us; speedup vs baseline: 1.0843x; 1.0843x over previous
//
#include <hip/hip_runtime.h>
#include <hip/hip_bf16.h>

#define N_NODES 50000
#define N_EDGES 800000
#define N_GRAPHS 64
#define CAP 64  // bucket capacity; deg ~ Binom(800k,1/50k), P(deg>64) ~ 1e-19

typedef __attribute__((ext_vector_type(8))) short bf16x8;
typedef __attribute__((ext_vector_type(4))) float f32x4;

#define AS1 __attribute__((address_space(1)))
#define AS3 __attribute__((address_space(3)))

__device__ __forceinline__ float bf2f(ushort u) { return __uint_as_float(((unsigned)u) << 16); }
__device__ __forceinline__ ushort f2bf(float f) {  // RNE
    unsigned b = __float_as_uint(f);
    b += 0x7fffu + ((b >> 16) & 1u);
    return (ushort)(b >> 16);
}

// async global->LDS, 16B per lane; LDS dest = wave-uniform base + lane*16 (linear)
__device__ __forceinline__ void gl_lds16(const ushort* g, ushort* l) {
    __builtin_amdgcn_global_load_lds((const AS1 void*)g, (AS3 void*)l, 16, 0, 0);
}

// ---------------------------------------------------------------- h0 = concat(x, pos) -> bf16
__global__ void build_h0(const float* __restrict__ x, const float* __restrict__ pos,
                         ushort* __restrict__ h0, int n) {
    const size_t total = (size_t)n * 128;
    for (size_t idx = (size_t)blockIdx.x * blockDim.x + threadIdx.x; idx < total;
         idx += (size_t)gridDim.x * blockDim.x) {
        int i = (int)(idx >> 7);
        int j = (int)(idx & 127);
        float v = (j < 125) ? x[(size_t)i * 125 + j] : pos[(size_t)i * 3 + (j - 125)];
        h0[idx] = f2bf(v);
    }
}

// ---------------------------------------------------------------- weights fp32 -> bf16
__global__ void convert_weights(const float* __restrict__ w0, const float* __restrict__ w1,
                                const float* __restrict__ w2, const float* __restrict__ w3,
                                const float* __restrict__ w4, const float* __restrict__ w5,
                                ushort* __restrict__ o) {
    const int total = 32768 * 2 + 65536 * 4;
    for (int i = blockIdx.x * blockDim.x + threadIdx.x; i < total; i += gridDim.x * blockDim.x) {
        float v;
        if (i < 32768) v = w0[i];
        else if (i < 65536) v = w1[i - 32768];
        else {
            int j = i - 65536;
            int m = j >> 16;
            int r = j & 65535;
            v = (m == 0) ? w2[r] : (m == 1) ? w3[r] : (m == 2) ? w4[r] : w5[r];
        }
        o[i] = f2bf(v);
    }
}

// ---------------------------------------------------------------- CSR build: single-pass buckets
// Fixed-capacity bucket per node (CAP=64); XCD-partitioned by dst range (blockIdx&7).
__global__ __launch_bounds__(256) void build_csr(const int* __restrict__ src,
                                                 const int* __restrict__ dst,
                                                 int* __restrict__ cnt,
                                                 ushort* __restrict__ csr, int e) {
    const int g = blockIdx.x & 7;
    const int bid = blockIdx.x >> 3;
    const int nb = gridDim.x >> 3;
    const int lo = g * (N_NODES / 8), hi = lo + (N_NODES / 8);
    for (int i = bid * blockDim.x + threadIdx.x; i < e; i += nb * blockDim.x) {
        const int d = dst[i];
        if (d >= lo && d < hi) {
            int pos = atomicAdd(&cnt[d], 1);
            if (pos < CAP) csr[(size_t)d * CAP + pos] = (ushort)src[i];
        }
    }
}

// ---------------------------------------------------------------- mean aggregation (gather, bf16)
// one wave per node; lane loads 16B (bf16x8). F=256: 2 edge-streams/wave; F=128: 4.
// Unroll x4 -> 8 (resp. 16) independent row loads in flight; singles tail.
// FETCH ~175MB is the structural floor (each XCD touches ~43k distinct rows).
template <int F>
__global__ __launch_bounds__(256) void csr_mean(const ushort* __restrict__ h,
                                                const int* __restrict__ cnt,
                                                const ushort* __restrict__ idx,
                                                ushort* __restrict__ s, int n) {
    const int node = blockIdx.x * 4 + (threadIdx.x >> 6);
    if (node >= n) return;
    const int lane = threadIdx.x & 63;
    constexpr int LPR = F / 8;        // lanes covering one row
    constexpr int EPW = 64 / LPR;     // edge streams per wave (2 or 4)
    const int sub = lane / LPR;       // edge-stream id
    const int l = lane % LPR;         // feature chunk (8 feats)
    const int b = node * CAP;
    const int c = min(cnt[node], CAP);

    float s0[8] = {}, s1[8] = {}, s2[8] = {}, s3[8] = {};
    const ushort* hl = h + (size_t)l * 8;
    int q = sub;
    for (; q + 3 * EPW < c; q += 4 * EPW) {
        int i0 = idx[b + q];
        int i1 = idx[b + q + EPW];
        int i2 = idx[b + q + 2 * EPW];
        int i3 = idx[b + q + 3 * EPW];
        bf16x8 v0 = *(const bf16x8*)(hl + (size_t)i0 * F);
        bf16x8 v1 = *(const bf16x8*)(hl + (size_t)i1 * F);
        bf16x8 v2 = *(const bf16x8*)(hl + (size_t)i2 * F);
        bf16x8 v3 = *(const bf16x8*)(hl + (size_t)i3 * F);
#pragma unroll
        for (int j = 0; j < 8; ++j) s0[j] += bf2f((ushort)v0[j]);
#pragma unroll
        for (int j = 0; j < 8; ++j) s1[j] += bf2f((ushort)v1[j]);
#pragma unroll
        for (int j = 0; j < 8; ++j) s2[j] += bf2f((ushort)v2[j]);
#pragma unroll
        for (int j = 0; j < 8; ++j) s3[j] += bf2f((ushort)v3[j]);
    }
    for (; q < c; q += EPW) {
        int i0 = idx[b + q];
        bf16x8 v0 = *(const bf16x8*)(hl + (size_t)i0 * F);
#pragma unroll
        for (int j = 0; j < 8; ++j) s0[j] += bf2f((ushort)v0[j]);
    }
    const float w = 1.0f / (float)max(c, 1);
    bf16x8 o;
#pragma unroll
    for (int j = 0; j < 8; ++j) {
        float a = (s0[j] + s1[j]) + (s2[j] + s3[j]);
        if constexpr (EPW == 4) a += __shfl_xor(a, 16);
        a += __shfl_xor(a, 32);
        o[j] = (short)f2bf(a * w);
    }
    if (sub == 0) *(bf16x8*)(s + (size_t)node * F + l * 8) = o;
}

// ---------------------------------------------------------------- fused SAGE GEMM (bf16 MFMA)
// 128x128 tile (R12-proven). 1-D grid with XCD-pairing swizzle: id = 16*(r/8) + 8*c + (r%8)
// puts both column-halves of row-panel r on the SAME XCD (ids congruent mod 8) and in the
// same dispatch window -> the second block reads the A-panel from that XCD's L2 instead of
// L3, halving A-panel L3 traffic. Pure locality remap; correctness independent of mapping.
__global__ __launch_bounds__(256, 3) void sage_gemm(
    const ushort* __restrict__ S, const ushort* __restrict__ H,
    const ushort* __restrict__ Wl, const ushort* __restrict__ Wr,
    const float* __restrict__ bias, ushort* __restrict__ O, int n, int F) {
    constexpr int BM = 128, BN = 128, BK = 64;
    __shared__ ushort As[BM * BK];
    __shared__ ushort Bs[BN * BK];
    const int id = blockIdx.x;
    const int r = (id >> 4) * 8 + (id & 7);       // row-panel
    const int cc = (id >> 3) & 1;                 // column half
    const int nrp = (n + BM - 1) / BM;            // 391
    if (r >= nrp) return;
    const int row0 = r * BM;
    const int col0 = cc * BN;
    const int tid = threadIdx.x;
    const int wid = tid >> 6;
    const int wr = wid >> 1;
    const int wc = wid & 1;
    const int lane = tid & 63;
    const int lr = lane & 15;
    const int lk = lane >> 4;
    const int lrow = lane >> 3;  // staging: row within 8-row stripe
    const int lgg = lane & 7;    // staging: granule (16B) within row

    f32x4 acc[4][4] = {};

    const int Ktot = 2 * F;
    for (int kb = 0; kb < Ktot; kb += BK) {
        const bool left = (kb < F);
        const int kofs = left ? kb : kb - F;
        const ushort* __restrict__ Ab = left ? S : H;
        const ushort* __restrict__ Wb = left ? Wl : Wr;
        // ---- stage 16KB A + 16KB B: each wave stages 4 8-row stripes per tile ----
#pragma unroll
        for (int p = 0; p < 4; ++p) {
            const int rb = (p * 4 + wid) * 8;  // stripe base row
            const int rr = rb + lrow;
            const int sg = (lgg ^ (rr & 7)) << 3;  // swizzled source granule (shorts)
            const int gr = min(row0 + rr, n - 1);
            gl_lds16(Ab + (size_t)gr * F + kofs + sg, &As[rb * 64]);
            gl_lds16(Wb + (size_t)(col0 + rr) * F + kofs + sg, &Bs[rb * 64]);
        }
        __syncthreads();
#pragma unroll
        for (int kh = 0; kh < 2; ++kh) {
            bf16x8 af[4], bg[4];
            const int g = kh * 4 + lk;  // source granule wanted
#pragma unroll
            for (int m = 0; m < 4; ++m) {
                const int ra = wr * 64 + m * 16 + lr;
                af[m] = *(const bf16x8*)&As[ra * 64 + ((g ^ (ra & 7)) << 3)];
            }
#pragma unroll
            for (int q = 0; q < 4; ++q) {
                const int rb2 = wc * 64 + q * 16 + lr;
                bg[q] = *(const bf16x8*)&Bs[rb2 * 64 + ((g ^ (rb2 & 7)) << 3)];
            }
#pragma unroll
            for (int m = 0; m < 4; ++m)
#pragma unroll
                for (int q = 0; q < 4; ++q)
                    acc[m][q] =
                        __builtin_amdgcn_mfma_f32_16x16x32_bf16(af[m], bg[q], acc[m][q], 0, 0, 0);
        }
        __syncthreads();
    }
    // epilogue: bias + relu -> bf16. C/D map: col = lane&15, row = (lane>>4)*4 + reg
#pragma unroll
    for (int q = 0; q < 4; ++q) {
        const int col = col0 + wc * 64 + q * 16 + lr;
        const float bv = bias[col];
#pragma unroll
        for (int m = 0; m < 4; ++m) {
            const int row = row0 + wr * 64 + m * 16 + lk * 4;
#pragma unroll
            for (int j = 0; j < 4; ++j) {
                if (row + j < n)
                    O[(size_t)(row + j) * 256 + col] = f2bf(fmaxf(acc[m][q][j] + bv, 0.f));
            }
        }
    }
}

// ---------------------------------------------------------------- global max pool (batch sorted)
__global__ __launch_bounds__(256) void pool_max(const ushort* __restrict__ h,
                                                const int* __restrict__ batch,
                                                int* __restrict__ gpool, int n) {
    const int CHUNK = 32;
    const int wave = threadIdx.x >> 6;
    const int lane = threadIdx.x & 63;
    const int c0 = (blockIdx.x * 4 + wave) * CHUNK;
    if (c0 >= n) return;
    const int c1 = min(c0 + CHUNK, n);
    const int fb = lane * 4;
    float m0 = 0.f, m1 = 0.f, m2 = 0.f, m3 = 0.f;
    int g = batch[c0];
    for (int i = c0; i < c1; ++i) {
        const int bg = batch[i];
        if (bg != g) {
            int* gp = &gpool[g * 256 + fb];
            atomicMax(gp + 0, __float_as_int(m0));
            atomicMax(gp + 1, __float_as_int(m1));
            atomicMax(gp + 2, __float_as_int(m2));
            atomicMax(gp + 3, __float_as_int(m3));
            m0 = m1 = m2 = m3 = 0.f;
            g = bg;
        }
        const ushort4 v = *(const ushort4*)(h + (size_t)i * 256 + fb);
        m0 = fmaxf(m0, bf2f(v.x));
        m1 = fmaxf(m1, bf2f(v.y));
        m2 = fmaxf(m2, bf2f(v.z));
        m3 = fmaxf(m3, bf2f(v.w));
    }
    int* gp = &gpool[g * 256 + fb];
    atomicMax(gp + 0, __float_as_int(m0));
    atomicMax(gp + 1, __float_as_int(m1));
    atomicMax(gp + 2, __float_as_int(m2));
    atomicMax(gp + 3, __float_as_int(m3));
}

// ---------------------------------------------------------------- head (fp32)
__global__ __launch_bounds__(256) void head_kernel(
    const float* __restrict__ gpool, const float* __restrict__ linW,
    const float* __restrict__ linb, const float* __restrict__ outW,
    const float* __restrict__ outb, float* __restrict__ out) {
    __shared__ float gin[256];
    __shared__ float gl[256];
    int g = blockIdx.x, t = threadIdx.x;
    gin[t] = gpool[g * 256 + t];
    __syncthreads();
    float acc = linb[t];
    const float* w = linW + (size_t)t * 256;
#pragma unroll 4
    for (int k = 0; k < 256; ++k) acc = fmaf(gin[k], w[k], acc);
    gl[t] = acc;
    __syncthreads();
    if (t < 160) {
        int o = t >> 4, s = t & 15;
        float p = 0.f;
        for (int k = s; k < 256; k += 16) p = fmaf(gl[k], outW[o * 256 + k], p);
        p += __shfl_down(p, 8, 16);
        p += __shfl_down(p, 4, 16);
        p += __shfl_down(p, 2, 16);
        p += __shfl_down(p, 1, 16);
        if (s == 0) out[g * 10 + o] = p + outb[o];
    }
}

// ---------------------------------------------------------------- launcher
extern "C" void kernel_launch(void* const* d_in, const int* in_sizes, int n_in,
                              void* d_out, int out_size, void* d_ws, size_t ws_size,
                              hipStream_t stream) {
    const float* x    = (const float*)d_in[0];
    const float* pos  = (const float*)d_in[1];
    const int* ei     = (const int*)d_in[2];
    const int* batch  = (const int*)d_in[3];
    const float* Wl0  = (const float*)d_in[4];
    const float* bl0  = (const float*)d_in[5];
    const float* Wr0  = (const float*)d_in[6];
    const float* Wl1  = (const float*)d_in[7];
    const float* bl1  = (const float*)d_in[8];
    const float* Wr1  = (const float*)d_in[9];
    const float* Wl2  = (const float*)d_in[10];
    const float* bl2  = (const float*)d_in[11];
    const float* Wr2  = (const float*)d_in[12];
    const float* linW = (const float*)d_in[13];
    const float* linb = (const float*)d_in[14];
    const float* outW = (const float*)d_in[15];
    const float* outb = (const float*)d_in[16];
    float* out = (float*)d_out;

    const int* src = ei;
    const int* dst = ei + N_EDGES;
    const int N = N_NODES, E = N_EDGES;

    // workspace layout
    ushort* hA   = (ushort*)d_ws;                // N*256 bf16
    ushort* hB   = hA + (size_t)N * 256;
    ushort* Sg   = hB + (size_t)N * 256;
    ushort* Wb   = Sg + (size_t)N * 256;         // 327680 shorts
    ushort* csr  = Wb + 327680;                  // N*CAP ushorts (6.4 MB)
    int* cnt     = (int*)(csr + (size_t)N * CAP);  // N
    int* gpool   = cnt + N;                      // 64*256

    ushort* Wl0b = Wb;
    ushort* Wr0b = Wb + 32768;
    ushort* Wl1b = Wb + 65536;
    ushort* Wr1b = Wb + 65536 + 65536;
    ushort* Wl2b = Wb + 65536 + 2 * 65536;
    ushort* Wr2b = Wb + 65536 + 3 * 65536;

    build_h0<<<dim3(1024), dim3(256), 0, stream>>>(x, pos, hA, N);
    convert_weights<<<dim3(640), dim3(256), 0, stream>>>(Wl0, Wr0, Wl1, Wr1, Wl2, Wr2, Wb);

    // CSR bucket build (dst-partitioned by XCD group), shared by all 3 layers
    hipMemsetAsync(cnt, 0, (size_t)N * sizeof(int), stream);
    build_csr<<<dim3(768), dim3(256), 0, stream>>>(src, dst, cnt, csr, E);

    // GEMM grid: 16 ids per 8 row-panels (2 col halves), ceil(391/8)=49 groups -> 784
    const dim3 gemm_grid(16 * (((N + 127) / 128 + 7) / 8)), blk(256);

    // layer 0: hA(128) -> hB(256)
    csr_mean<128><<<dim3((N + 3) / 4), blk, 0, stream>>>(hA, cnt, csr, Sg, N);
    sage_gemm<<<gemm_grid, blk, 0, stream>>>(Sg, hA, Wl0b, Wr0b, bl0, hB, N, 128);

    // layer 1: hB(256) -> hA(256)
    csr_mean<256><<<dim3((N + 3) / 4), blk, 0, stream>>>(hB, cnt, csr, Sg, N);
    sage_gemm<<<gemm_grid, blk, 0, stream>>>(Sg, hB, Wl1b, Wr1b, bl1, hA, N, 256);

    // layer 2: hA(256) -> hB(256)
    csr_mean<256><<<dim3((N + 3) / 4), blk, 0, stream>>>(hA, cnt, csr, Sg, N);
    sage_gemm<<<gemm_grid, blk, 0, stream>>>(Sg, hA, Wl2b, Wr2b, bl2, hB, N, 256);

    // pool + head
    hipMemsetAsync(gpool, 0, (size_t)N_GRAPHS * 256 * sizeof(int), stream);
    pool_max<<<dim3((N + 127) / 128), blk, 0, stream>>>(hB, batch, gpool, N);
    head_kernel<<<dim3(N_GRAPHS), blk, 0, stream>>>((const float*)gpool, linW, linb, outW, outb,
                                                    out);
}

// Round 15
// 308.928 us; speedup vs baseline: 1.0893x; 1.0047x over previous
//
#include <hip/hip_runtime.h>
#include <hip/hip_bf16.h>

#define N_NODES 50000
#define N_EDGES 800000
#define N_GRAPHS 64
#define CAP 64  // bucket capacity; deg ~ Binom(800k,1/50k), P(deg>64) ~ 1e-19

typedef __attribute__((ext_vector_type(8))) short bf16x8;
typedef __attribute__((ext_vector_type(4))) float f32x4;

#define AS1 __attribute__((address_space(1)))
#define AS3 __attribute__((address_space(3)))

__device__ __forceinline__ float bf2f(ushort u) { return __uint_as_float(((unsigned)u) << 16); }
__device__ __forceinline__ ushort f2bf(float f) {  // RNE
    unsigned b = __float_as_uint(f);
    b += 0x7fffu + ((b >> 16) & 1u);
    return (ushort)(b >> 16);
}

// async global->LDS, 16B per lane; LDS dest = wave-uniform base + lane*16 (linear)
__device__ __forceinline__ void gl_lds16(const ushort* g, ushort* l) {
    __builtin_amdgcn_global_load_lds((const AS1 void*)g, (AS3 void*)l, 16, 0, 0);
}

// ---------------------------------------------------------------- h0 = concat(x, pos) -> bf16
__global__ void build_h0(const float* __restrict__ x, const float* __restrict__ pos,
                         ushort* __restrict__ h0, int n) {
    const size_t total = (size_t)n * 128;
    for (size_t idx = (size_t)blockIdx.x * blockDim.x + threadIdx.x; idx < total;
         idx += (size_t)gridDim.x * blockDim.x) {
        int i = (int)(idx >> 7);
        int j = (int)(idx & 127);
        float v = (j < 125) ? x[(size_t)i * 125 + j] : pos[(size_t)i * 3 + (j - 125)];
        h0[idx] = f2bf(v);
    }
}

// ---------------------------------------------------------------- weights fp32 -> bf16
__global__ void convert_weights(const float* __restrict__ w0, const float* __restrict__ w1,
                                const float* __restrict__ w2, const float* __restrict__ w3,
                                const float* __restrict__ w4, const float* __restrict__ w5,
                                ushort* __restrict__ o) {
    const int total = 32768 * 2 + 65536 * 4;
    for (int i = blockIdx.x * blockDim.x + threadIdx.x; i < total; i += gridDim.x * blockDim.x) {
        float v;
        if (i < 32768) v = w0[i];
        else if (i < 65536) v = w1[i - 32768];
        else {
            int j = i - 65536;
            int m = j >> 16;
            int r = j & 65535;
            v = (m == 0) ? w2[r] : (m == 1) ? w3[r] : (m == 2) ? w4[r] : w5[r];
        }
        o[i] = f2bf(v);
    }
}

// ---------------------------------------------------------------- edge pack + zero-init
// ds[i] = (dst<<16)|src (both < 65536): halves build_csr's 8x streamed bytes.
// Also absorbs the cnt/gpool memsets (runs before build_csr / pool_max).
__global__ __launch_bounds__(256) void pack_edges(const int* __restrict__ src,
                                                  const int* __restrict__ dst,
                                                  unsigned* __restrict__ ds,
                                                  int* __restrict__ cnt,
                                                  int* __restrict__ gpool, int e) {
    for (int i = blockIdx.x * blockDim.x + threadIdx.x; i < e; i += gridDim.x * blockDim.x) {
        ds[i] = ((unsigned)dst[i] << 16) | (unsigned)src[i];
        if (i < N_NODES) cnt[i] = 0;
        if (i < N_GRAPHS * 256) gpool[i] = 0;
    }
}

// ---------------------------------------------------------------- CSR build: single-pass buckets
// Fixed-capacity bucket per node (CAP=64); XCD-partitioned by dst range (blockIdx&7).
__global__ __launch_bounds__(256) void build_csr(const unsigned* __restrict__ ds,
                                                 int* __restrict__ cnt,
                                                 ushort* __restrict__ csr, int e) {
    const int g = blockIdx.x & 7;
    const int bid = blockIdx.x >> 3;
    const int nb = gridDim.x >> 3;
    const unsigned lo = (unsigned)(g * (N_NODES / 8)), hi = lo + (N_NODES / 8);
    for (int i = bid * blockDim.x + threadIdx.x; i < e; i += nb * blockDim.x) {
        const unsigned v = ds[i];
        const unsigned d = v >> 16;
        if (d >= lo && d < hi) {
            int pos = atomicAdd(&cnt[d], 1);
            if (pos < CAP) csr[(size_t)d * CAP + pos] = (ushort)(v & 0xffffu);
        }
    }
}

// ---------------------------------------------------------------- mean aggregation (gather, bf16)
// one wave per node; lane loads 16B (bf16x8). F=256: 2 edge-streams/wave; F=128: 4.
// Unroll x4 -> 8 (resp. 16) independent row loads in flight; singles tail.
// FETCH ~175MB is the structural floor (each XCD touches ~43k distinct rows);
// serve rate ~3.7 TB/s confirmed BW-wall across R8/R10 occupancy variants.
template <int F>
__global__ __launch_bounds__(256) void csr_mean(const ushort* __restrict__ h,
                                                const int* __restrict__ cnt,
                                                const ushort* __restrict__ idx,
                                                ushort* __restrict__ s, int n) {
    const int node = blockIdx.x * 4 + (threadIdx.x >> 6);
    if (node >= n) return;
    const int lane = threadIdx.x & 63;
    constexpr int LPR = F / 8;        // lanes covering one row
    constexpr int EPW = 64 / LPR;     // edge streams per wave (2 or 4)
    const int sub = lane / LPR;       // edge-stream id
    const int l = lane % LPR;         // feature chunk (8 feats)
    const int b = node * CAP;
    const int c = min(cnt[node], CAP);

    float s0[8] = {}, s1[8] = {}, s2[8] = {}, s3[8] = {};
    const ushort* hl = h + (size_t)l * 8;
    int q = sub;
    for (; q + 3 * EPW < c; q += 4 * EPW) {
        int i0 = idx[b + q];
        int i1 = idx[b + q + EPW];
        int i2 = idx[b + q + 2 * EPW];
        int i3 = idx[b + q + 3 * EPW];
        bf16x8 v0 = *(const bf16x8*)(hl + (size_t)i0 * F);
        bf16x8 v1 = *(const bf16x8*)(hl + (size_t)i1 * F);
        bf16x8 v2 = *(const bf16x8*)(hl + (size_t)i2 * F);
        bf16x8 v3 = *(const bf16x8*)(hl + (size_t)i3 * F);
#pragma unroll
        for (int j = 0; j < 8; ++j) s0[j] += bf2f((ushort)v0[j]);
#pragma unroll
        for (int j = 0; j < 8; ++j) s1[j] += bf2f((ushort)v1[j]);
#pragma unroll
        for (int j = 0; j < 8; ++j) s2[j] += bf2f((ushort)v2[j]);
#pragma unroll
        for (int j = 0; j < 8; ++j) s3[j] += bf2f((ushort)v3[j]);
    }
    for (; q < c; q += EPW) {
        int i0 = idx[b + q];
        bf16x8 v0 = *(const bf16x8*)(hl + (size_t)i0 * F);
#pragma unroll
        for (int j = 0; j < 8; ++j) s0[j] += bf2f((ushort)v0[j]);
    }
    const float w = 1.0f / (float)max(c, 1);
    bf16x8 o;
#pragma unroll
    for (int j = 0; j < 8; ++j) {
        float a = (s0[j] + s1[j]) + (s2[j] + s3[j]);
        if constexpr (EPW == 4) a += __shfl_xor(a, 16);
        a += __shfl_xor(a, 32);
        o[j] = (short)f2bf(a * w);
    }
    if (sub == 0) *(bf16x8*)(s + (size_t)node * F + l * 8) = o;
}

// ---------------------------------------------------------------- fused SAGE GEMM (bf16 MFMA)
// 128x128 tile. 1-D grid with XCD-pairing swizzle: id = 16*(r/8) + 8*c + (r%8) puts both
// column-halves of row-panel r on the SAME XCD (ids congruent mod 8, same dispatch window)
// -> second block reads the A-panel from that XCD's L2 (halves A-panel L3 traffic).
__global__ __launch_bounds__(256, 3) void sage_gemm(
    const ushort* __restrict__ S, const ushort* __restrict__ H,
    const ushort* __restrict__ Wl, const ushort* __restrict__ Wr,
    const float* __restrict__ bias, ushort* __restrict__ O, int n, int F) {
    constexpr int BM = 128, BN = 128, BK = 64;
    __shared__ ushort As[BM * BK];
    __shared__ ushort Bs[BN * BK];
    const int id = blockIdx.x;
    const int r = (id >> 4) * 8 + (id & 7);       // row-panel
    const int cc = (id >> 3) & 1;                 // column half
    const int nrp = (n + BM - 1) / BM;            // 391
    if (r >= nrp) return;
    const int row0 = r * BM;
    const int col0 = cc * BN;
    const int tid = threadIdx.x;
    const int wid = tid >> 6;
    const int wr = wid >> 1;
    const int wc = wid & 1;
    const int lane = tid & 63;
    const int lr = lane & 15;
    const int lk = lane >> 4;
    const int lrow = lane >> 3;  // staging: row within 8-row stripe
    const int lgg = lane & 7;    // staging: granule (16B) within row

    f32x4 acc[4][4] = {};

    const int Ktot = 2 * F;
    for (int kb = 0; kb < Ktot; kb += BK) {
        const bool left = (kb < F);
        const int kofs = left ? kb : kb - F;
        const ushort* __restrict__ Ab = left ? S : H;
        const ushort* __restrict__ Wb = left ? Wl : Wr;
        // ---- stage 16KB A + 16KB B: each wave stages 4 8-row stripes per tile ----
#pragma unroll
        for (int p = 0; p < 4; ++p) {
            const int rb = (p * 4 + wid) * 8;  // stripe base row
            const int rr = rb + lrow;
            const int sg = (lgg ^ (rr & 7)) << 3;  // swizzled source granule (shorts)
            const int gr = min(row0 + rr, n - 1);
            gl_lds16(Ab + (size_t)gr * F + kofs + sg, &As[rb * 64]);
            gl_lds16(Wb + (size_t)(col0 + rr) * F + kofs + sg, &Bs[rb * 64]);
        }
        __syncthreads();
#pragma unroll
        for (int kh = 0; kh < 2; ++kh) {
            bf16x8 af[4], bg[4];
            const int g = kh * 4 + lk;  // source granule wanted
#pragma unroll
            for (int m = 0; m < 4; ++m) {
                const int ra = wr * 64 + m * 16 + lr;
                af[m] = *(const bf16x8*)&As[ra * 64 + ((g ^ (ra & 7)) << 3)];
            }
#pragma unroll
            for (int q = 0; q < 4; ++q) {
                const int rb2 = wc * 64 + q * 16 + lr;
                bg[q] = *(const bf16x8*)&Bs[rb2 * 64 + ((g ^ (rb2 & 7)) << 3)];
            }
#pragma unroll
            for (int m = 0; m < 4; ++m)
#pragma unroll
                for (int q = 0; q < 4; ++q)
                    acc[m][q] =
                        __builtin_amdgcn_mfma_f32_16x16x32_bf16(af[m], bg[q], acc[m][q], 0, 0, 0);
        }
        __syncthreads();
    }
    // epilogue: bias + relu -> bf16. C/D map: col = lane&15, row = (lane>>4)*4 + reg
#pragma unroll
    for (int q = 0; q < 4; ++q) {
        const int col = col0 + wc * 64 + q * 16 + lr;
        const float bv = bias[col];
#pragma unroll
        for (int m = 0; m < 4; ++m) {
            const int row = row0 + wr * 64 + m * 16 + lk * 4;
#pragma unroll
            for (int j = 0; j < 4; ++j) {
                if (row + j < n)
                    O[(size_t)(row + j) * 256 + col] = f2bf(fmaxf(acc[m][q][j] + bv, 0.f));
            }
        }
    }
}

// ---------------------------------------------------------------- global max pool (batch sorted)
// CHUNK=16 -> 782 blocks (~3/CU, avoids 1.5-block quantization of CHUNK=32).
__global__ __launch_bounds__(256) void pool_max(const ushort* __restrict__ h,
                                                const int* __restrict__ batch,
                                                int* __restrict__ gpool, int n) {
    const int CHUNK = 16;
    const int wave = threadIdx.x >> 6;
    const int lane = threadIdx.x & 63;
    const int c0 = (blockIdx.x * 4 + wave) * CHUNK;
    if (c0 >= n) return;
    const int c1 = min(c0 + CHUNK, n);
    const int fb = lane * 4;
    float m0 = 0.f, m1 = 0.f, m2 = 0.f, m3 = 0.f;
    int g = batch[c0];
    for (int i = c0; i < c1; ++i) {
        const int bg = batch[i];
        if (bg != g) {
            int* gp = &gpool[g * 256 + fb];
            atomicMax(gp + 0, __float_as_int(m0));
            atomicMax(gp + 1, __float_as_int(m1));
            atomicMax(gp + 2, __float_as_int(m2));
            atomicMax(gp + 3, __float_as_int(m3));
            m0 = m1 = m2 = m3 = 0.f;
            g = bg;
        }
        const ushort4 v = *(const ushort4*)(h + (size_t)i * 256 + fb);
        m0 = fmaxf(m0, bf2f(v.x));
        m1 = fmaxf(m1, bf2f(v.y));
        m2 = fmaxf(m2, bf2f(v.z));
        m3 = fmaxf(m3, bf2f(v.w));
    }
    int* gp = &gpool[g * 256 + fb];
    atomicMax(gp + 0, __float_as_int(m0));
    atomicMax(gp + 1, __float_as_int(m1));
    atomicMax(gp + 2, __float_as_int(m2));
    atomicMax(gp + 3, __float_as_int(m3));
}

// ---------------------------------------------------------------- head (fp32)
__global__ __launch_bounds__(256) void head_kernel(
    const float* __restrict__ gpool, const float* __restrict__ linW,
    const float* __restrict__ linb, const float* __restrict__ outW,
    const float* __restrict__ outb, float* __restrict__ out) {
    __shared__ float gin[256];
    __shared__ float gl[256];
    int g = blockIdx.x, t = threadIdx.x;
    gin[t] = gpool[g * 256 + t];
    __syncthreads();
    float acc = linb[t];
    const float* w = linW + (size_t)t * 256;
#pragma unroll 4
    for (int k = 0; k < 256; ++k) acc = fmaf(gin[k], w[k], acc);
    gl[t] = acc;
    __syncthreads();
    if (t < 160) {
        int o = t >> 4, s = t & 15;
        float p = 0.f;
        for (int k = s; k < 256; k += 16) p = fmaf(gl[k], outW[o * 256 + k], p);
        p += __shfl_down(p, 8, 16);
        p += __shfl_down(p, 4, 16);
        p += __shfl_down(p, 2, 16);
        p += __shfl_down(p, 1, 16);
        if (s == 0) out[g * 10 + o] = p + outb[o];
    }
}

// ---------------------------------------------------------------- launcher
extern "C" void kernel_launch(void* const* d_in, const int* in_sizes, int n_in,
                              void* d_out, int out_size, void* d_ws, size_t ws_size,
                              hipStream_t stream) {
    const float* x    = (const float*)d_in[0];
    const float* pos  = (const float*)d_in[1];
    const int* ei     = (const int*)d_in[2];
    const int* batch  = (const int*)d_in[3];
    const float* Wl0  = (const float*)d_in[4];
    const float* bl0  = (const float*)d_in[5];
    const float* Wr0  = (const float*)d_in[6];
    const float* Wl1  = (const float*)d_in[7];
    const float* bl1  = (const float*)d_in[8];
    const float* Wr1  = (const float*)d_in[9];
    const float* Wl2  = (const float*)d_in[10];
    const float* bl2  = (const float*)d_in[11];
    const float* Wr2  = (const float*)d_in[12];
    const float* linW = (const float*)d_in[13];
    const float* linb = (const float*)d_in[14];
    const float* outW = (const float*)d_in[15];
    const float* outb = (const float*)d_in[16];
    float* out = (float*)d_out;

    const int* src = ei;
    const int* dst = ei + N_EDGES;
    const int N = N_NODES, E = N_EDGES;

    // workspace layout
    ushort* hA   = (ushort*)d_ws;                  // N*256 bf16
    ushort* hB   = hA + (size_t)N * 256;
    ushort* Sg   = hB + (size_t)N * 256;
    ushort* Wb   = Sg + (size_t)N * 256;           // 327680 shorts
    ushort* csr  = Wb + 327680;                    // N*CAP ushorts (6.4 MB)
    int* cnt     = (int*)(csr + (size_t)N * CAP);  // N
    int* gpool   = cnt + N;                        // 64*256
    unsigned* ds = (unsigned*)(gpool + 64 * 256);  // E packed edges (3.2 MB)

    ushort* Wl0b = Wb;
    ushort* Wr0b = Wb + 32768;
    ushort* Wl1b = Wb + 65536;
    ushort* Wr1b = Wb + 65536 + 65536;
    ushort* Wl2b = Wb + 65536 + 2 * 65536;
    ushort* Wr2b = Wb + 65536 + 3 * 65536;

    build_h0<<<dim3(1024), dim3(256), 0, stream>>>(x, pos, hA, N);
    convert_weights<<<dim3(640), dim3(256), 0, stream>>>(Wl0, Wr0, Wl1, Wr1, Wl2, Wr2, Wb);

    // edge pack (+ cnt/gpool zero-init), then bucket CSR build (dst-partitioned by XCD group)
    pack_edges<<<dim3(1024), dim3(256), 0, stream>>>(src, dst, ds, cnt, gpool, E);
    build_csr<<<dim3(768), dim3(256), 0, stream>>>(ds, cnt, csr, E);

    // GEMM grid: 16 ids per 8 row-panels (2 col halves), ceil(391/8)=49 groups -> 784
    const dim3 gemm_grid(16 * (((N + 127) / 128 + 7) / 8)), blk(256);

    // layer 0: hA(128) -> hB(256)
    csr_mean<128><<<dim3((N + 3) / 4), blk, 0, stream>>>(hA, cnt, csr, Sg, N);
    sage_gemm<<<gemm_grid, blk, 0, stream>>>(Sg, hA, Wl0b, Wr0b, bl0, hB, N, 128);

    // layer 1: hB(256) -> hA(256)
    csr_mean<256><<<dim3((N + 3) / 4), blk, 0, stream>>>(hB, cnt, csr, Sg, N);
    sage_gemm<<<gemm_grid, blk, 0, stream>>>(Sg, hB, Wl1b, Wr1b, bl1, hA, N, 256);

    // layer 2: hA(256) -> hB(256)
    csr_mean<256><<<dim3((N + 3) / 4), blk, 0, stream>>>(hA, cnt, csr, Sg, N);
    sage_gemm<<<gemm_grid, blk, 0, stream>>>(Sg, hA, Wl2b, Wr2b, bl2, hB, N, 256);

    // pool + head
    pool_max<<<dim3((N + 63) / 64), blk, 0, stream>>>(hB, batch, gpool, N);
    head_kernel<<<dim3(N_GRAPHS), blk, 0, stream>>>((const float*)gpool, linW, linb, outW, outb,
                                                    out);
}